// Round 9
// baseline (233.408 us; speedup 1.0000x reference)
//
#include <hip/hip_runtime.h>
#include <hip/hip_bf16.h>
#include <stdint.h>

// B=16, S=512, D=512, H=8, DH=64. Float tensors fp32; mask int32; out fp32.
// Internals: bf16 MFMA operands, fp32 accumulation.

typedef __hip_bfloat16 bf16;
typedef __bf16 bf16x8 __attribute__((ext_vector_type(8)));
typedef float f32x4 __attribute__((ext_vector_type(4)));

#define MFMA16(a, b, c) __builtin_amdgcn_mfma_f32_16x16x32_bf16((a), (b), (c), 0, 0, 0)
// Compiler-only fence (r7-proven): stops LLVM hoisting cross-lane ds_reads
// above ds_writes (per-lane alias analysis can't see the cross-lane dep);
// emits zero instructions so global loads stay in flight.
#define WAVE_LDS_FENCE() asm volatile("" ::: "memory")

static __device__ __forceinline__ bf16 f2b(float v) { return __float2bfloat16(v); }
static __device__ __forceinline__ bf16x8 ld8(const bf16* p) { return *(const bf16x8*)p; }
static __device__ __forceinline__ uint16_t f2bu(float v) {
  return __hip_bfloat16_raw(__float2bfloat16(v)).x;
}
static __device__ __forceinline__ float bu2f(uint32_t u) {
  union { uint32_t i; float f; } c;
  c.i = u << 16;
  return c.f;
}

// ---------------------------------------------------------------- transpose + cast
__global__ __launch_bounds__(256) void transpose512(
    const float* __restrict__ W0, const float* __restrict__ W1,
    const float* __restrict__ W2, const float* __restrict__ W3,
    bf16* __restrict__ T0, bf16* __restrict__ T1,
    bf16* __restrict__ T2, bf16* __restrict__ T3) {
  __shared__ float t[32][33];
  const float* src; bf16* dst;
  switch (blockIdx.z) {
    case 0: src = W0; dst = T0; break;
    case 1: src = W1; dst = T1; break;
    case 2: src = W2; dst = T2; break;
    default: src = W3; dst = T3; break;
  }
  int tx = threadIdx.x, ty = threadIdx.y;  // 32 x 8
  int n0 = blockIdx.x * 32, k0 = blockIdx.y * 32;
#pragma unroll
  for (int i = 0; i < 4; i++) {
    int kk = ty * 4 + i;
    t[kk][tx] = src[(k0 + kk) * 512 + n0 + tx];
  }
  __syncthreads();
#pragma unroll
  for (int i = 0; i < 4; i++) {
    int nn = ty * 4 + i;
    dst[(n0 + nn) * 512 + k0 + tx] = f2b(t[tx][nn]);
  }
}

// ---------------------------------------------------------------- mask -> bitmask
__global__ __launch_bounds__(256) void mask_pack(const int* __restrict__ mask,
                                                 uint32_t* __restrict__ bits) {
  size_t t = (size_t)blockIdx.x * 256 + threadIdx.x;
  int mv = mask[t];
  unsigned long long bal = __ballot(mv != 0);
  if ((threadIdx.x & 63) == 0) {
    ((unsigned long long*)bits)[t >> 6] = bal;
  }
}

// ---------------------------------------------------------------- bit transpose
// tbits[row*16 + l] bit j = mask bit of key (l + 16*j).
__global__ __launch_bounds__(256) void mask_transpose(const uint32_t* __restrict__ bits,
                                                      uint32_t* __restrict__ tbits) {
  int t = blockIdx.x * 256 + threadIdx.x;  // 8192 rows * 16 lanes
  int row = t >> 4, l = t & 15;
  const uint32_t* in = bits + row * 16;
  uint32_t o = 0;
#pragma unroll
  for (int jj = 0; jj < 32; jj++) {
    int key = l + 16 * jj;
    o |= ((in[key >> 5] >> (key & 31)) & 1u) << jj;
  }
  tbits[t] = o;
}

// ---------------------------------------------------------------- LayerNorm(x) -> h (bf16)
__global__ __launch_bounds__(256) void ln_rows(
    const float* __restrict__ x, const float* __restrict__ g,
    const float* __restrict__ be, bf16* __restrict__ h) {
  int row = blockIdx.x;
  int tid = threadIdx.x;
  const float* xr = x + (size_t)row * 512;
  float v0 = xr[tid], v1 = xr[tid + 256];
  float s = v0 + v1, s2 = v0 * v0 + v1 * v1;
#pragma unroll
  for (int m = 1; m < 64; m <<= 1) {
    s += __shfl_xor(s, m);
    s2 += __shfl_xor(s2, m);
  }
  __shared__ float rs[4], rs2[4];
  int w = tid >> 6;
  if ((tid & 63) == 0) { rs[w] = s; rs2[w] = s2; }
  __syncthreads();
  s = rs[0] + rs[1] + rs[2] + rs[3];
  s2 = rs2[0] + rs2[1] + rs2[2] + rs2[3];
  float mean = s * (1.0f / 512.0f);
  float var = s2 * (1.0f / 512.0f) - mean * mean;
  float rstd = rsqrtf(var + 1e-5f);
  bf16* hr = h + (size_t)row * 512;
  hr[tid] = f2b((v0 - mean) * rstd * g[tid] + be[tid]);
  hr[tid + 256] = f2b((v1 - mean) * rstd * g[tid + 256] + be[tid + 256]);
}

// ---------------------------------------------------------------- QKV GEMM (unchanged)
__global__ __launch_bounds__(256) void gemm_qkv(
    const bf16* __restrict__ hm,
    const bf16* __restrict__ WT0, const bf16* __restrict__ WT1, const bf16* __restrict__ WT2,
    const float* __restrict__ bq, const float* __restrict__ bk, const float* __restrict__ bv,
    bf16* __restrict__ outq, bf16* __restrict__ outk, bf16* __restrict__ outvT) {
  const int sel = blockIdx.z;
  const bf16* WT = sel == 0 ? WT0 : (sel == 1 ? WT1 : WT2);
  const float* bias = sel == 0 ? bq : (sel == 1 ? bk : bv);
  __shared__ __align__(16) bf16 As[128][40];
  __shared__ __align__(16) bf16 Bs[128][40];
  int tid = threadIdx.x;
  int w = tid >> 6, lane = tid & 63, q4 = lane >> 4, l16 = lane & 15;
  int wr = w >> 1, wc = w & 1;
  int m0 = blockIdx.x * 128, n0 = blockIdx.y * 128;
  f32x4 acc[4][4];
#pragma unroll
  for (int i = 0; i < 4; i++)
#pragma unroll
    for (int j = 0; j < 4; j++) acc[i][j] = (f32x4){0.f, 0.f, 0.f, 0.f};

  for (int kc = 0; kc < 16; kc++) {
    int k0 = kc * 32;
#pragma unroll
    for (int u = tid; u < 512; u += 256) {
      int row = u >> 2, c8 = (u & 3) * 8;
      *(bf16x8*)&As[row][c8] = ld8(&hm[(size_t)(m0 + row) * 512 + k0 + c8]);
      *(bf16x8*)&Bs[row][c8] = ld8(&WT[(size_t)(n0 + row) * 512 + k0 + c8]);
    }
    __syncthreads();
    bf16x8 af[4], bfr[4];
#pragma unroll
    for (int rt = 0; rt < 4; rt++) af[rt] = ld8(&As[wr * 64 + rt * 16 + l16][q4 * 8]);
#pragma unroll
    for (int nt = 0; nt < 4; nt++) bfr[nt] = ld8(&Bs[wc * 64 + nt * 16 + l16][q4 * 8]);
#pragma unroll
    for (int rt = 0; rt < 4; rt++)
#pragma unroll
      for (int nt = 0; nt < 4; nt++) acc[rt][nt] = MFMA16(af[rt], bfr[nt], acc[rt][nt]);
    __syncthreads();
  }

#pragma unroll
  for (int rt = 0; rt < 4; rt++) {
    int mbase = m0 + wr * 64 + rt * 16 + q4 * 4;
    int b = mbase >> 9, s0 = mbase & 511;
#pragma unroll
    for (int nt = 0; nt < 4; nt++) {
      int n = n0 + wc * 64 + nt * 16 + l16;
      float bsv = bias[n];
      int hh = n >> 6, dh = n & 63;
      if (sel == 2) {
        union { bf16 q[4]; uint2 u; } pk;
#pragma unroll
        for (int r = 0; r < 4; r++) pk.q[r] = f2b(acc[rt][nt][r] + bsv);
        *(uint2*)(outvT + ((size_t)((b * 8 + hh) * 64 + dh)) * 512 + s0) = pk.u;
      } else {
        bf16* dst = sel == 0 ? outq : outk;
        float scale = sel == 0 ? 0.125f : 1.0f;
#pragma unroll
        for (int r = 0; r < 4; r++)
          dst[((size_t)((b * 8 + hh) * 512 + s0 + r)) * 64 + dh] =
              f2b((acc[rt][nt][r] + bsv) * scale);
      }
    }
  }
}

// ---------------------------------------------------------------- fused attention v9
// Block = 256 thr (4 waves) x 64 q-rows x one bh; grid 1024 (XCD-swizzled).
// k/v staged cooperatively through LDS (r8's L2-traffic win) BUT scores live
// bf16-packed in registers (64 u32/lane) — r8's 67.6 KB ST is gone, killing
// its bank conflicts and the 2-blocks/CU occupancy cap. LN+mask+exp is pure
// register math. P->A-layout via tiny per-wave PBT (r4 pattern, r7 fences).
// LDS ~18.5 KB -> 3 blocks/CU (launch_bounds(256,3), no spill headroom risk).
__global__ __launch_bounds__(256, 3) void attn_fused(
    const bf16* __restrict__ q, const bf16* __restrict__ k, const bf16* __restrict__ vT,
    const uint32_t* __restrict__ tbits, const float* __restrict__ lg,
    const float* __restrict__ lb, bf16* __restrict__ ctx) {
  const int id = blockIdx.x;              // 0..1023
  const int xcd = id & 7;
  const int j = id >> 3;                  // 0..127
  const int mt = j & 7;                   // 8 m-tiles of 64 rows
  const int bh = ((j >> 3) << 3) | xcd;   // bh%8 == xcd
  const int m0 = mt * 64;
  const int b = bh >> 3, hh = bh & 7;
  const int tid = threadIdx.x;
  const int w = tid >> 6, lane = tid & 63, q4 = lane >> 4, l16 = lane & 15;

  __shared__ __align__(16) bf16 SB[2][2560];  // k chunk [32][72] / v chunk [64][40]
  __shared__ uint16_t PBT[4][32][18];         // per-wave P transpose (r4 pattern)
  __shared__ float SG[512], SBt[512];         // LN gamma/beta

  SG[tid] = lg[tid];
  SG[tid + 256] = lg[tid + 256];
  SBt[tid] = lb[tid];
  SBt[tid + 256] = lb[tid + 256];

  const bf16* qb = q + ((size_t)bh * 512 + m0 + w * 16) * 64;
  const bf16* kb = k + (size_t)bh * 512 * 64;
  const bf16* vb = vT + (size_t)bh * 64 * 512;

  bf16x8 aq0 = ld8(qb + (size_t)l16 * 64 + q4 * 8);
  bf16x8 aq1 = ld8(qb + (size_t)l16 * 64 + 32 + q4 * 8);

  // per-lane mask bits: row w*16+q4*4+r; bit j <-> key j*16+l16
  uint32_t tb[4];
#pragma unroll
  for (int r = 0; r < 4; r++)
    tb[r] = tbits[((size_t)b * 512 + m0 + w * 16 + q4 * 4 + r) * 16 + l16];

  // stage k chunk 0
  {
    int key0 = tid >> 3, dh8 = (tid & 7) * 8;
    *(bf16x8*)&SB[0][key0 * 72 + dh8] = ld8(kb + (size_t)key0 * 64 + dh8);
  }
  __syncthreads();

  // ---- pass 1: QK^T -> bf16-packed registers + stats
  uint32_t sc[64];
  float s[4] = {0.f, 0.f, 0.f, 0.f}, s2[4] = {0.f, 0.f, 0.f, 0.f};
#pragma unroll
  for (int c = 0; c < 16; c++) {
    const int buf = c & 1;
    if (c < 15) {
      int key0 = tid >> 3, dh8 = (tid & 7) * 8;
      *(bf16x8*)&SB[buf ^ 1][key0 * 72 + dh8] =
          ld8(kb + (size_t)((c + 1) * 32 + key0) * 64 + dh8);
    }
#pragma unroll
    for (int kg = 0; kg < 2; kg++) {
      const bf16* kp = &SB[buf][(kg * 16 + l16) * 72];
      bf16x8 b0 = ld8(kp + q4 * 8);
      bf16x8 b1 = ld8(kp + 32 + q4 * 8);
      f32x4 acc = (f32x4){0.f, 0.f, 0.f, 0.f};
      acc = MFMA16(aq0, b0, acc);
      acc = MFMA16(aq1, b1, acc);
#pragma unroll
      for (int r = 0; r < 4; r++) {
        float v = acc[r];
        s[r] += v;
        s2[r] += v * v;
      }
      sc[c * 4 + kg * 2] = (uint32_t)f2bu(acc[0]) | ((uint32_t)f2bu(acc[1]) << 16);
      sc[c * 4 + kg * 2 + 1] = (uint32_t)f2bu(acc[2]) | ((uint32_t)f2bu(acc[3]) << 16);
    }
    __syncthreads();
  }

  // ---- stats (wave-local 16-lane reduce)
  float mean[4], rstd[4];
#pragma unroll
  for (int r = 0; r < 4; r++) {
    float a = s[r], a2 = s2[r];
#pragma unroll
    for (int mm = 1; mm < 16; mm <<= 1) {
      a += __shfl_xor(a, mm);
      a2 += __shfl_xor(a2, mm);
    }
    float mu = a * (1.0f / 512.0f);
    float var = a2 * (1.0f / 512.0f) - mu * mu;
    mean[r] = mu;
    rstd[r] = rsqrtf(var + 1e-5f);
  }

  // ---- phase 2: LN + mask + exp, registers only
  float se[4] = {0.f, 0.f, 0.f, 0.f};
#pragma unroll
  for (int c = 0; c < 16; c++)
#pragma unroll
    for (int kg = 0; kg < 2; kg++) {
      int key = c * 32 + kg * 16 + l16;
      float g = SG[key], be = SBt[key];
      int bit = 2 * c + kg;
      uint32_t d0 = sc[c * 4 + kg * 2], d1 = sc[c * 4 + kg * 2 + 1];
      float v[4] = {bu2f(d0 & 0xffff), bu2f(d0 >> 16), bu2f(d1 & 0xffff), bu2f(d1 >> 16)};
      uint16_t p[4];
#pragma unroll
      for (int r = 0; r < 4; r++) {
        float t = (v[r] - mean[r]) * rstd[r] * g + be;
        t = ((tb[r] >> bit) & 1u) ? t : -1.0e9f;
        float pf = __expf(t);
        se[r] += pf;
        p[r] = f2bu(pf);
      }
      sc[c * 4 + kg * 2] = (uint32_t)p[0] | ((uint32_t)p[1] << 16);
      sc[c * 4 + kg * 2 + 1] = (uint32_t)p[2] | ((uint32_t)p[3] << 16);
    }
  float inv[4];
#pragma unroll
  for (int r = 0; r < 4; r++) {
    float a = se[r];
#pragma unroll
    for (int mm = 1; mm < 16; mm <<= 1) a += __shfl_xor(a, mm);
    inv[r] = 1.0f / a;
  }

  // ---- pass 2: PV; v staged as [dh][key] chunks, P via per-wave PBT
  {
    int dh = tid >> 2, kk8 = (tid & 3) * 8;
    *(bf16x8*)&SB[0][dh * 40 + kk8] = ld8(vb + (size_t)dh * 512 + kk8);
  }
  __syncthreads();

  f32x4 o[4];
#pragma unroll
  for (int nt = 0; nt < 4; nt++) o[nt] = (f32x4){0.f, 0.f, 0.f, 0.f};

#pragma unroll
  for (int c = 0; c < 16; c++) {
    const int buf = c & 1;
    if (c < 15) {
      int dh = tid >> 2, kk8 = (tid & 3) * 8;
      *(bf16x8*)&SB[buf ^ 1][dh * 40 + kk8] =
          ld8(vb + (size_t)dh * 512 + (c + 1) * 32 + kk8);
    }
    // P chunk -> per-wave transpose buffer
    *(uint32_t*)&PBT[w][l16][q4 * 4] = sc[c * 4 + 0];
    *(uint32_t*)&PBT[w][l16][q4 * 4 + 2] = sc[c * 4 + 1];
    *(uint32_t*)&PBT[w][16 + l16][q4 * 4] = sc[c * 4 + 2];
    *(uint32_t*)&PBT[w][16 + l16][q4 * 4 + 2] = sc[c * 4 + 3];
    WAVE_LDS_FENCE();  // order ds_write -> cross-lane ds_read (r5 lesson)
    union { uint16_t u[8]; bf16x8 v; } af;
#pragma unroll
    for (int jj = 0; jj < 8; jj++) af.u[jj] = PBT[w][q4 * 8 + jj][l16];
    WAVE_LDS_FENCE();  // WAR vs next chunk's writes
#pragma unroll
    for (int nt = 0; nt < 4; nt++) {
      bf16x8 bv8 = ld8(&SB[buf][(nt * 16 + l16) * 40 + q4 * 8]);
      o[nt] = MFMA16(af.v, bv8, o[nt]);
    }
    __syncthreads();
  }

  // ---- epilogue: scale by 1/sum, write ctx
  bf16* cb = ctx + ((size_t)b * 512 + m0 + w * 16) * 512 + hh * 64;
#pragma unroll
  for (int nt = 0; nt < 4; nt++)
#pragma unroll
    for (int r = 0; r < 4; r++)
      cb[(size_t)(q4 * 4 + r) * 512 + nt * 16 + l16] = f2b(o[nt][r] * inv[r]);
}

// ---------------------------------------------------------------- out proj + residual (fp32 out)
__global__ __launch_bounds__(256) void gemm_out(
    const bf16* __restrict__ ctx, const bf16* __restrict__ WT,
    const float* __restrict__ bd, const float* __restrict__ x, float* __restrict__ out) {
  __shared__ __align__(16) bf16 As[128][40];
  __shared__ __align__(16) bf16 Bs[128][40];
  int tid = threadIdx.x;
  int w = tid >> 6, lane = tid & 63, q4 = lane >> 4, l16 = lane & 15;
  int wr = w >> 1, wc = w & 1;
  int m0 = blockIdx.x * 128, n0 = blockIdx.y * 128;
  f32x4 acc[4][4];
#pragma unroll
  for (int i = 0; i < 4; i++)
#pragma unroll
    for (int j = 0; j < 4; j++) acc[i][j] = (f32x4){0.f, 0.f, 0.f, 0.f};

  for (int kc = 0; kc < 16; kc++) {
    int k0 = kc * 32;
#pragma unroll
    for (int u = tid; u < 512; u += 256) {
      int row = u >> 2, c8 = (u & 3) * 8;
      *(bf16x8*)&As[row][c8] = ld8(&ctx[(size_t)(m0 + row) * 512 + k0 + c8]);
      *(bf16x8*)&Bs[row][c8] = ld8(&WT[(size_t)(n0 + row) * 512 + k0 + c8]);
    }
    __syncthreads();
    bf16x8 af[4], bfr[4];
#pragma unroll
    for (int rt = 0; rt < 4; rt++) af[rt] = ld8(&As[wr * 64 + rt * 16 + l16][q4 * 8]);
#pragma unroll
    for (int nt = 0; nt < 4; nt++) bfr[nt] = ld8(&Bs[wc * 64 + nt * 16 + l16][q4 * 8]);
#pragma unroll
    for (int rt = 0; rt < 4; rt++)
#pragma unroll
      for (int nt = 0; nt < 4; nt++) acc[rt][nt] = MFMA16(af[rt], bfr[nt], acc[rt][nt]);
    __syncthreads();
  }
#pragma unroll
  for (int rt = 0; rt < 4; rt++) {
    int mbase = m0 + wr * 64 + rt * 16 + q4 * 4;
#pragma unroll
    for (int nt = 0; nt < 4; nt++) {
      int n = n0 + wc * 64 + nt * 16 + l16;
      float bsv = bd[n];
#pragma unroll
      for (int r = 0; r < 4; r++) {
        size_t idx = (size_t)(mbase + r) * 512 + n;
        out[idx] = acc[rt][nt][r] + bsv + x[idx];
      }
    }
  }
}

// ---------------------------------------------------------------- launch
extern "C" void kernel_launch(void* const* d_in, const int* in_sizes, int n_in,
                              void* d_out, int out_size, void* d_ws, size_t ws_size,
                              hipStream_t stream) {
  const float* x = (const float*)d_in[0];
  const int* mask = (const int*)d_in[1];
  const float* ln_g = (const float*)d_in[2];
  const float* ln_b = (const float*)d_in[3];
  const float* lna_g = (const float*)d_in[4];
  const float* lna_b = (const float*)d_in[5];
  const float* Wq = (const float*)d_in[6];
  const float* bq = (const float*)d_in[7];
  const float* Wk = (const float*)d_in[8];
  const float* bk = (const float*)d_in[9];
  const float* Wv = (const float*)d_in[10];
  const float* bv = (const float*)d_in[11];
  const float* Wd = (const float*)d_in[12];
  const float* bd = (const float*)d_in[13];

  char* ws = (char*)d_ws;
  const size_t MB = 1024 * 1024;
  if (ws_size < 44 * MB) return;
  bf16* h = (bf16*)(ws);                 // 8 MB  [8192,512]
  bf16* qd = (bf16*)(ws + 8 * MB);       // 8 MB  [B,H,S,DH]
  bf16* kd = (bf16*)(ws + 16 * MB);      // 8 MB  [B,H,S,DH]
  bf16* vTd = (bf16*)(ws + 24 * MB);     // 8 MB  [B,H,DH,S]
  bf16* ctx = (bf16*)(ws + 32 * MB);     // 8 MB  [B,S,D] bf16
  bf16* WqT = (bf16*)(ws + 40 * MB);
  bf16* WkT = (bf16*)(ws + 40 * MB + 512 * 1024);
  bf16* WvT = (bf16*)(ws + 40 * MB + 1024 * 1024);
  bf16* WdT = (bf16*)(ws + 40 * MB + 1536 * 1024);
  uint32_t* bits = (uint32_t*)(ws + 42 * MB);                // 512 KB
  uint32_t* tbits = (uint32_t*)(ws + 42 * MB + 512 * 1024);  // 512 KB

  transpose512<<<dim3(16, 16, 4), dim3(32, 8), 0, stream>>>(Wq, Wk, Wv, Wd, WqT, WkT, WvT, WdT);
  mask_pack<<<16384, 256, 0, stream>>>(mask, bits);
  mask_transpose<<<512, 256, 0, stream>>>(bits, tbits);
  ln_rows<<<8192, 256, 0, stream>>>(x, ln_g, ln_b, h);
  gemm_qkv<<<dim3(64, 4, 3), 256, 0, stream>>>(h, WqT, WkT, WvT, bq, bk, bv, qd, kd, vTd);
  attn_fused<<<1024, 256, 0, stream>>>(qd, kd, vTd, tbits, lna_g, lna_b, ctx);
  gemm_out<<<dim3(64, 4), 256, 0, stream>>>(ctx, WdT, bd, x, (float*)d_out);
}

// Round 10
// 191.938 us; speedup vs baseline: 1.2161x; 1.2161x over previous
//
#include <hip/hip_runtime.h>
#include <hip/hip_bf16.h>
#include <stdint.h>

// B=16, S=512, D=512, H=8, DH=64. Float tensors fp32; mask int32; out fp32.
// Internals: bf16 MFMA operands, fp32 accumulation.

typedef __hip_bfloat16 bf16;
typedef __bf16 bf16x8 __attribute__((ext_vector_type(8)));
typedef float f32x4 __attribute__((ext_vector_type(4)));

#define MFMA16(a, b, c) __builtin_amdgcn_mfma_f32_16x16x32_bf16((a), (b), (c), 0, 0, 0)

static __device__ __forceinline__ bf16 f2b(float v) { return __float2bfloat16(v); }
static __device__ __forceinline__ bf16x8 ld8(const bf16* p) { return *(const bf16x8*)p; }
static __device__ __forceinline__ uint16_t f2bu(float v) {
  return __hip_bfloat16_raw(__float2bfloat16(v)).x;
}
static __device__ __forceinline__ float bu2f(uint32_t u) {
  union { uint32_t i; float f; } c;
  c.i = u << 16;
  return c.f;
}
// m97-style async global->LDS, 16 B/lane. HW semantics: wave-uniform LDS base
// + lane*16 (m104/m108) — caller must pass per-lane lds ptrs that are exactly
// base + lane*16 (our staging maps are linear in the lane index).
static __device__ __forceinline__ void stage16(const bf16* g, bf16* l) {
  __builtin_amdgcn_global_load_lds(
      (const __attribute__((address_space(1))) void*)g,
      (__attribute__((address_space(3))) void*)l, 16, 0, 0);
}

// ---------------------------------------------------------------- transpose + cast
__global__ __launch_bounds__(256) void transpose512(
    const float* __restrict__ W0, const float* __restrict__ W1,
    const float* __restrict__ W2, const float* __restrict__ W3,
    bf16* __restrict__ T0, bf16* __restrict__ T1,
    bf16* __restrict__ T2, bf16* __restrict__ T3) {
  __shared__ float t[32][33];
  const float* src; bf16* dst;
  switch (blockIdx.z) {
    case 0: src = W0; dst = T0; break;
    case 1: src = W1; dst = T1; break;
    case 2: src = W2; dst = T2; break;
    default: src = W3; dst = T3; break;
  }
  int tx = threadIdx.x, ty = threadIdx.y;  // 32 x 8
  int n0 = blockIdx.x * 32, k0 = blockIdx.y * 32;
#pragma unroll
  for (int i = 0; i < 4; i++) {
    int kk = ty * 4 + i;
    t[kk][tx] = src[(k0 + kk) * 512 + n0 + tx];
  }
  __syncthreads();
#pragma unroll
  for (int i = 0; i < 4; i++) {
    int nn = ty * 4 + i;
    dst[(n0 + nn) * 512 + k0 + tx] = f2b(t[tx][nn]);
  }
}

// ---------------------------------------------------------------- mask -> transposed bitmask
// tbits[row*16 + l] bit j = (mask[row*512 + l + 16*j] != 0)  (fused pack+transpose)
__global__ __launch_bounds__(256) void mask_bits(const int* __restrict__ mask,
                                                 uint32_t* __restrict__ tbits) {
  int t = blockIdx.x * 256 + threadIdx.x;  // 8192 rows * 16 lanes
  int row = t >> 4, l = t & 15;
  const int* mrow = mask + (size_t)row * 512 + l;
  uint32_t o = 0;
#pragma unroll
  for (int j = 0; j < 32; j++) o |= (mrow[j * 16] != 0 ? 1u : 0u) << j;
  tbits[t] = o;
}

// ---------------------------------------------------------------- LayerNorm(x) -> h (bf16)
__global__ __launch_bounds__(256) void ln_rows(
    const float* __restrict__ x, const float* __restrict__ g,
    const float* __restrict__ be, bf16* __restrict__ h) {
  int row = blockIdx.x;
  int tid = threadIdx.x;
  const float* xr = x + (size_t)row * 512;
  float v0 = xr[tid], v1 = xr[tid + 256];
  float s = v0 + v1, s2 = v0 * v0 + v1 * v1;
#pragma unroll
  for (int m = 1; m < 64; m <<= 1) {
    s += __shfl_xor(s, m);
    s2 += __shfl_xor(s2, m);
  }
  __shared__ float rs[4], rs2[4];
  int w = tid >> 6;
  if ((tid & 63) == 0) { rs[w] = s; rs2[w] = s2; }
  __syncthreads();
  s = rs[0] + rs[1] + rs[2] + rs[3];
  s2 = rs2[0] + rs2[1] + rs2[2] + rs2[3];
  float mean = s * (1.0f / 512.0f);
  float var = s2 * (1.0f / 512.0f) - mean * mean;
  float rstd = rsqrtf(var + 1e-5f);
  bf16* hr = h + (size_t)row * 512;
  hr[tid] = f2b((v0 - mean) * rstd * g[tid] + be[tid]);
  hr[tid + 256] = f2b((v1 - mean) * rstd * g[tid + 256] + be[tid + 256]);
}

// ---------------------------------------------------------------- QKV GEMM, global_load_lds staging
// m97 recipe: unpadded LDS tiles (layout = lane-linear, required by the async
// DMA), 2-barrier K-loop, ds_read_b128 fragments. Bank conflicts on frag reads
// are accepted (m97: 874 TF with the same pattern).
__global__ __launch_bounds__(256) void gemm_qkv(
    const bf16* __restrict__ hm,
    const bf16* __restrict__ WT0, const bf16* __restrict__ WT1, const bf16* __restrict__ WT2,
    const float* __restrict__ bq, const float* __restrict__ bk, const float* __restrict__ bv,
    bf16* __restrict__ outq, bf16* __restrict__ outk, bf16* __restrict__ outvT) {
  const int sel = blockIdx.z;
  const bf16* WT = sel == 0 ? WT0 : (sel == 1 ? WT1 : WT2);
  const float* bias = sel == 0 ? bq : (sel == 1 ? bk : bv);
  __shared__ __align__(16) bf16 As[128 * 32];
  __shared__ __align__(16) bf16 Bs[128 * 32];
  int tid = threadIdx.x;
  int w = tid >> 6, lane = tid & 63, q4 = lane >> 4, l16 = lane & 15;
  int wr = w >> 1, wc = w & 1;
  int m0 = blockIdx.x * 128, n0 = blockIdx.y * 128;
  f32x4 acc[4][4];
#pragma unroll
  for (int i = 0; i < 4; i++)
#pragma unroll
    for (int j = 0; j < 4; j++) acc[i][j] = (f32x4){0.f, 0.f, 0.f, 0.f};

  for (int kc = 0; kc < 16; kc++) {
    int k0 = kc * 32;
#pragma unroll
    for (int u0 = 0; u0 < 2; u0++) {
      int e = u0 * 256 + tid;          // 16B unit index; LDS dst = base + e*16B
      int row = e >> 2, c8 = (e & 3) * 8;
      stage16(&hm[(size_t)(m0 + row) * 512 + k0 + c8], &As[e * 8]);
      stage16(&WT[(size_t)(n0 + row) * 512 + k0 + c8], &Bs[e * 8]);
    }
    __syncthreads();  // drains vmcnt (global_load_lds) before use
    bf16x8 af[4], bfr[4];
#pragma unroll
    for (int rt = 0; rt < 4; rt++)
      af[rt] = ld8(&As[(wr * 64 + rt * 16 + l16) * 32 + q4 * 8]);
#pragma unroll
    for (int nt = 0; nt < 4; nt++)
      bfr[nt] = ld8(&Bs[(wc * 64 + nt * 16 + l16) * 32 + q4 * 8]);
#pragma unroll
    for (int rt = 0; rt < 4; rt++)
#pragma unroll
      for (int nt = 0; nt < 4; nt++) acc[rt][nt] = MFMA16(af[rt], bfr[nt], acc[rt][nt]);
    __syncthreads();
  }

#pragma unroll
  for (int rt = 0; rt < 4; rt++) {
    int mbase = m0 + wr * 64 + rt * 16 + q4 * 4;
    int b = mbase >> 9, s0 = mbase & 511;
#pragma unroll
    for (int nt = 0; nt < 4; nt++) {
      int n = n0 + wc * 64 + nt * 16 + l16;
      float bsv = bias[n];
      int hh = n >> 6, dh = n & 63;
      if (sel == 2) {
        union { bf16 q[4]; uint2 u; } pk;
#pragma unroll
        for (int r = 0; r < 4; r++) pk.q[r] = f2b(acc[rt][nt][r] + bsv);
        *(uint2*)(outvT + ((size_t)((b * 8 + hh) * 64 + dh)) * 512 + s0) = pk.u;
      } else {
        bf16* dst = sel == 0 ? outq : outk;
        float scale = sel == 0 ? 0.125f : 1.0f;
#pragma unroll
        for (int r = 0; r < 4; r++)
          dst[((size_t)((b * 8 + hh) * 512 + s0 + r)) * 64 + dh] =
              f2b((acc[rt][nt][r] + bsv) * scale);
      }
    }
  }
}

// ---------------------------------------------------------------- fused attention (r8 exact)
// Block = 256 thr (4 waves) x 64 q-rows x one bh; grid 1024 (XCD-swizzled).
// k/v chunks staged ONCE per block into LDS (coalesced) and shared by all 4
// waves; scores (64x512 bf16) live in LDS (ST); exp in place; softmax scale
// folded into epilogue. Proven 52 us (r8). r9's registers-scores variant
// spilled sc[64] to scratch (104 MB WRITE_SIZE) — do not repeat.
__global__ __launch_bounds__(256, 2) void attn_fused(
    const bf16* __restrict__ q, const bf16* __restrict__ k, const bf16* __restrict__ vT,
    const uint32_t* __restrict__ tbits, const float* __restrict__ lg,
    const float* __restrict__ lb, bf16* __restrict__ ctx) {
  const int id = blockIdx.x;              // 0..1023
  const int xcd = id & 7;
  const int j = id >> 3;                  // 0..127
  const int mt = j & 7;                   // 8 m-tiles of 64 rows
  const int bh = ((j >> 3) << 3) | xcd;   // bh%8 == xcd
  const int m0 = mt * 64;
  const int b = bh >> 3, hh = bh & 7;
  const int tid = threadIdx.x;
  const int w = tid >> 6, lane = tid & 63, q4 = lane >> 4, l16 = lane & 15;

  __shared__ uint16_t ST[512][66];              // 67.6 KB: scores -> probs (bf16 bits)
  __shared__ __align__(16) bf16 SB[2][2560];    // 10 KB: k chunk [32][72] / v chunk [64][40]

  const bf16* qb = q + ((size_t)bh * 512 + m0 + w * 16) * 64;
  const bf16* kb = k + (size_t)bh * 512 * 64;
  const bf16* vb = vT + (size_t)bh * 64 * 512;

  bf16x8 aq0 = ld8(qb + (size_t)l16 * 64 + q4 * 8);
  bf16x8 aq1 = ld8(qb + (size_t)l16 * 64 + 32 + q4 * 8);

  uint32_t tb[4];
#pragma unroll
  for (int r = 0; r < 4; r++)
    tb[r] = tbits[((size_t)b * 512 + m0 + w * 16 + q4 * 4 + r) * 16 + l16];

  const int col = w * 16 + q4 * 4;

  {
    int key0 = tid >> 3, dh8 = (tid & 7) * 8;
    *(bf16x8*)&SB[0][key0 * 72 + dh8] = ld8(kb + (size_t)key0 * 64 + dh8);
  }
  __syncthreads();

  float s[4] = {0.f, 0.f, 0.f, 0.f}, s2[4] = {0.f, 0.f, 0.f, 0.f};
  for (int c = 0; c < 16; c++) {
    const int buf = c & 1;
    if (c < 15) {
      int key0 = tid >> 3, dh8 = (tid & 7) * 8;
      *(bf16x8*)&SB[buf ^ 1][key0 * 72 + dh8] =
          ld8(kb + (size_t)((c + 1) * 32 + key0) * 64 + dh8);
    }
#pragma unroll
    for (int kg = 0; kg < 2; kg++) {
      const bf16* kp = &SB[buf][(kg * 16 + l16) * 72];
      bf16x8 b0 = ld8(kp + q4 * 8);
      bf16x8 b1 = ld8(kp + 32 + q4 * 8);
      f32x4 acc = (f32x4){0.f, 0.f, 0.f, 0.f};
      acc = MFMA16(aq0, b0, acc);
      acc = MFMA16(aq1, b1, acc);
#pragma unroll
      for (int r = 0; r < 4; r++) {
        float v = acc[r];
        s[r] += v;
        s2[r] += v * v;
      }
      int key = c * 32 + kg * 16 + l16;
      *(uint32_t*)&ST[key][col] = (uint32_t)f2bu(acc[0]) | ((uint32_t)f2bu(acc[1]) << 16);
      *(uint32_t*)&ST[key][col + 2] = (uint32_t)f2bu(acc[2]) | ((uint32_t)f2bu(acc[3]) << 16);
    }
    __syncthreads();
  }

  float mean[4], rstd[4];
#pragma unroll
  for (int r = 0; r < 4; r++) {
    float a = s[r], a2 = s2[r];
#pragma unroll
    for (int mm = 1; mm < 16; mm <<= 1) {
      a += __shfl_xor(a, mm);
      a2 += __shfl_xor(a2, mm);
    }
    float mu = a * (1.0f / 512.0f);
    float var = a2 * (1.0f / 512.0f) - mu * mu;
    mean[r] = mu;
    rstd[r] = rsqrtf(var + 1e-5f);
  }

  float se[4] = {0.f, 0.f, 0.f, 0.f};
#pragma unroll
  for (int i = 0; i < 32; i++) {
    int key = i * 16 + l16;
    float g = lg[key], be = lb[key];
    uint32_t d0 = *(uint32_t*)&ST[key][col];
    uint32_t d1 = *(uint32_t*)&ST[key][col + 2];
    float v[4] = {bu2f(d0 & 0xffff), bu2f(d0 >> 16), bu2f(d1 & 0xffff), bu2f(d1 >> 16)};
    uint16_t p[4];
#pragma unroll
    for (int r = 0; r < 4; r++) {
      float t = (v[r] - mean[r]) * rstd[r] * g + be;
      t = ((tb[r] >> i) & 1u) ? t : -1.0e9f;
      float pf = __expf(t);
      se[r] += pf;
      p[r] = f2bu(pf);
    }
    *(uint32_t*)&ST[key][col] = (uint32_t)p[0] | ((uint32_t)p[1] << 16);
    *(uint32_t*)&ST[key][col + 2] = (uint32_t)p[2] | ((uint32_t)p[3] << 16);
  }
  float inv[4];
#pragma unroll
  for (int r = 0; r < 4; r++) {
    float a = se[r];
#pragma unroll
    for (int mm = 1; mm < 16; mm <<= 1) a += __shfl_xor(a, mm);
    inv[r] = 1.0f / a;
  }

  {
    int dh = tid >> 2, kk8 = (tid & 3) * 8;
    *(bf16x8*)&SB[0][dh * 40 + kk8] = ld8(vb + (size_t)dh * 512 + kk8);
  }
  __syncthreads();

  f32x4 o[4];
#pragma unroll
  for (int nt = 0; nt < 4; nt++) o[nt] = (f32x4){0.f, 0.f, 0.f, 0.f};

  for (int c = 0; c < 16; c++) {
    const int buf = c & 1;
    if (c < 15) {
      int dh = tid >> 2, kk8 = (tid & 3) * 8;
      *(bf16x8*)&SB[buf ^ 1][dh * 40 + kk8] =
          ld8(vb + (size_t)dh * 512 + (c + 1) * 32 + kk8);
    }
    union { uint16_t u[8]; bf16x8 v; } af;
#pragma unroll
    for (int jj = 0; jj < 8; jj++) af.u[jj] = ST[c * 32 + q4 * 8 + jj][w * 16 + l16];
#pragma unroll
    for (int nt = 0; nt < 4; nt++) {
      bf16x8 bv8 = ld8(&SB[buf][(nt * 16 + l16) * 40 + q4 * 8]);
      o[nt] = MFMA16(af.v, bv8, o[nt]);
    }
    __syncthreads();
  }

  bf16* cb = ctx + ((size_t)b * 512 + m0 + w * 16) * 512 + hh * 64;
#pragma unroll
  for (int nt = 0; nt < 4; nt++)
#pragma unroll
    for (int r = 0; r < 4; r++)
      cb[(size_t)(q4 * 4 + r) * 512 + nt * 16 + l16] = f2b(o[nt][r] * inv[r]);
}

// ---------------------------------------------------------------- out proj + residual (fp32 out)
__global__ __launch_bounds__(256) void gemm_out(
    const bf16* __restrict__ ctx, const bf16* __restrict__ WT,
    const float* __restrict__ bd, const float* __restrict__ x, float* __restrict__ out) {
  __shared__ __align__(16) bf16 As[128 * 32];
  __shared__ __align__(16) bf16 Bs[128 * 32];
  int tid = threadIdx.x;
  int w = tid >> 6, lane = tid & 63, q4 = lane >> 4, l16 = lane & 15;
  int wr = w >> 1, wc = w & 1;
  int m0 = blockIdx.x * 128, n0 = blockIdx.y * 128;
  f32x4 acc[4][4];
#pragma unroll
  for (int i = 0; i < 4; i++)
#pragma unroll
    for (int j = 0; j < 4; j++) acc[i][j] = (f32x4){0.f, 0.f, 0.f, 0.f};

  for (int kc = 0; kc < 16; kc++) {
    int k0 = kc * 32;
#pragma unroll
    for (int u0 = 0; u0 < 2; u0++) {
      int e = u0 * 256 + tid;
      int row = e >> 2, c8 = (e & 3) * 8;
      stage16(&ctx[(size_t)(m0 + row) * 512 + k0 + c8], &As[e * 8]);
      stage16(&WT[(size_t)(n0 + row) * 512 + k0 + c8], &Bs[e * 8]);
    }
    __syncthreads();
    bf16x8 af[4], bfr[4];
#pragma unroll
    for (int rt = 0; rt < 4; rt++)
      af[rt] = ld8(&As[(wr * 64 + rt * 16 + l16) * 32 + q4 * 8]);
#pragma unroll
    for (int nt = 0; nt < 4; nt++)
      bfr[nt] = ld8(&Bs[(wc * 64 + nt * 16 + l16) * 32 + q4 * 8]);
#pragma unroll
    for (int rt = 0; rt < 4; rt++)
#pragma unroll
      for (int nt = 0; nt < 4; nt++) acc[rt][nt] = MFMA16(af[rt], bfr[nt], acc[rt][nt]);
    __syncthreads();
  }
#pragma unroll
  for (int rt = 0; rt < 4; rt++) {
    int mbase = m0 + wr * 64 + rt * 16 + q4 * 4;
#pragma unroll
    for (int nt = 0; nt < 4; nt++) {
      int n = n0 + wc * 64 + nt * 16 + l16;
      float bsv = bd[n];
#pragma unroll
      for (int r = 0; r < 4; r++) {
        size_t idx = (size_t)(mbase + r) * 512 + n;
        out[idx] = acc[rt][nt][r] + bsv + x[idx];
      }
    }
  }
}

// ---------------------------------------------------------------- launch
extern "C" void kernel_launch(void* const* d_in, const int* in_sizes, int n_in,
                              void* d_out, int out_size, void* d_ws, size_t ws_size,
                              hipStream_t stream) {
  const float* x = (const float*)d_in[0];
  const int* mask = (const int*)d_in[1];
  const float* ln_g = (const float*)d_in[2];
  const float* ln_b = (const float*)d_in[3];
  const float* lna_g = (const float*)d_in[4];
  const float* lna_b = (const float*)d_in[5];
  const float* Wq = (const float*)d_in[6];
  const float* bq = (const float*)d_in[7];
  const float* Wk = (const float*)d_in[8];
  const float* bk = (const float*)d_in[9];
  const float* Wv = (const float*)d_in[10];
  const float* bv = (const float*)d_in[11];
  const float* Wd = (const float*)d_in[12];
  const float* bd = (const float*)d_in[13];

  char* ws = (char*)d_ws;
  const size_t MB = 1024 * 1024;
  if (ws_size < 44 * MB) return;
  bf16* h = (bf16*)(ws);                 // 8 MB  [8192,512]
  bf16* qd = (bf16*)(ws + 8 * MB);       // 8 MB  [B,H,S,DH]
  bf16* kd = (bf16*)(ws + 16 * MB);      // 8 MB  [B,H,S,DH]
  bf16* vTd = (bf16*)(ws + 24 * MB);     // 8 MB  [B,H,DH,S]
  bf16* ctx = (bf16*)(ws + 32 * MB);     // 8 MB  [B,S,D] bf16
  bf16* WqT = (bf16*)(ws + 40 * MB);
  bf16* WkT = (bf16*)(ws + 40 * MB + 512 * 1024);
  bf16* WvT = (bf16*)(ws + 40 * MB + 1024 * 1024);
  bf16* WdT = (bf16*)(ws + 40 * MB + 1536 * 1024);
  uint32_t* tbits = (uint32_t*)(ws + 42 * MB);  // 512 KB

  transpose512<<<dim3(16, 16, 4), dim3(32, 8), 0, stream>>>(Wq, Wk, Wv, Wd, WqT, WkT, WvT, WdT);
  mask_bits<<<512, 256, 0, stream>>>(mask, tbits);
  ln_rows<<<8192, 256, 0, stream>>>(x, ln_g, ln_b, h);
  gemm_qkv<<<dim3(64, 4, 3), 256, 0, stream>>>(h, WqT, WkT, WvT, bq, bk, bv, qd, kd, vTd);
  attn_fused<<<1024, 256, 0, stream>>>(qd, kd, vTd, tbits, lna_g, lna_b, ctx);
  gemm_out<<<dim3(64, 4), 256, 0, stream>>>(ctx, WdT, bd, x, (float*)d_out);
}

// Round 11
// 189.752 us; speedup vs baseline: 1.2301x; 1.0115x over previous
//
#include <hip/hip_runtime.h>
#include <hip/hip_bf16.h>
#include <stdint.h>

// B=16, S=512, D=512, H=8, DH=64. Float tensors fp32; mask int32; out fp32.
// Internals: bf16 MFMA operands, fp32 accumulation.

typedef __hip_bfloat16 bf16;
typedef __bf16 bf16x8 __attribute__((ext_vector_type(8)));
typedef float f32x4 __attribute__((ext_vector_type(4)));

#define MFMA16(a, b, c) __builtin_amdgcn_mfma_f32_16x16x32_bf16((a), (b), (c), 0, 0, 0)

static __device__ __forceinline__ bf16 f2b(float v) { return __float2bfloat16(v); }
static __device__ __forceinline__ bf16x8 ld8(const bf16* p) { return *(const bf16x8*)p; }
static __device__ __forceinline__ uint16_t f2bu(float v) {
  return __hip_bfloat16_raw(__float2bfloat16(v)).x;
}
static __device__ __forceinline__ float bu2f(uint32_t u) {
  union { uint32_t i; float f; } c;
  c.i = u << 16;
  return c.f;
}
// m97-style async global->LDS, 16 B/lane (wave-uniform base + lane*16).
static __device__ __forceinline__ void stage16(const bf16* g, bf16* l) {
  __builtin_amdgcn_global_load_lds(
      (const __attribute__((address_space(1))) void*)g,
      (__attribute__((address_space(3))) void*)l, 16, 0, 0);
}

// ---------------------------------------------------------------- transpose + cast
__global__ __launch_bounds__(256) void transpose512(
    const float* __restrict__ W0, const float* __restrict__ W1,
    const float* __restrict__ W2, const float* __restrict__ W3,
    bf16* __restrict__ T0, bf16* __restrict__ T1,
    bf16* __restrict__ T2, bf16* __restrict__ T3) {
  __shared__ float t[32][33];
  const float* src; bf16* dst;
  switch (blockIdx.z) {
    case 0: src = W0; dst = T0; break;
    case 1: src = W1; dst = T1; break;
    case 2: src = W2; dst = T2; break;
    default: src = W3; dst = T3; break;
  }
  int tx = threadIdx.x, ty = threadIdx.y;  // 32 x 8
  int n0 = blockIdx.x * 32, k0 = blockIdx.y * 32;
#pragma unroll
  for (int i = 0; i < 4; i++) {
    int kk = ty * 4 + i;
    t[kk][tx] = src[(k0 + kk) * 512 + n0 + tx];
  }
  __syncthreads();
#pragma unroll
  for (int i = 0; i < 4; i++) {
    int nn = ty * 4 + i;
    dst[(n0 + nn) * 512 + k0 + tx] = f2b(t[tx][nn]);
  }
}

// ---------------------------------------------------------------- mask -> transposed bitmask
// tbits[row*16 + l] bit j = (mask[row*512 + l + 16*j] != 0)
__global__ __launch_bounds__(256) void mask_bits(const int* __restrict__ mask,
                                                 uint32_t* __restrict__ tbits) {
  int t = blockIdx.x * 256 + threadIdx.x;  // 8192 rows * 16 lanes
  int row = t >> 4, l = t & 15;
  const int* mrow = mask + (size_t)row * 512 + l;
  uint32_t o = 0;
#pragma unroll
  for (int j = 0; j < 32; j++) o |= (mrow[j * 16] != 0 ? 1u : 0u) << j;
  tbits[t] = o;
}

// ---------------------------------------------------------------- LayerNorm(x) -> h (bf16)
__global__ __launch_bounds__(256) void ln_rows(
    const float* __restrict__ x, const float* __restrict__ g,
    const float* __restrict__ be, bf16* __restrict__ h) {
  int row = blockIdx.x;
  int tid = threadIdx.x;
  const float* xr = x + (size_t)row * 512;
  float v0 = xr[tid], v1 = xr[tid + 256];
  float s = v0 + v1, s2 = v0 * v0 + v1 * v1;
#pragma unroll
  for (int m = 1; m < 64; m <<= 1) {
    s += __shfl_xor(s, m);
    s2 += __shfl_xor(s2, m);
  }
  __shared__ float rs[4], rs2[4];
  int w = tid >> 6;
  if ((tid & 63) == 0) { rs[w] = s; rs2[w] = s2; }
  __syncthreads();
  s = rs[0] + rs[1] + rs[2] + rs[3];
  s2 = rs2[0] + rs2[1] + rs2[2] + rs2[3];
  float mean = s * (1.0f / 512.0f);
  float var = s2 * (1.0f / 512.0f) - mean * mean;
  float rstd = rsqrtf(var + 1e-5f);
  bf16* hr = h + (size_t)row * 512;
  hr[tid] = f2b((v0 - mean) * rstd * g[tid] + be[tid]);
  hr[tid + 256] = f2b((v1 - mean) * rstd * g[tid + 256] + be[tid + 256]);
}

// ---------------------------------------------------------------- QKV GEMM
// K-loop: m97 recipe (global_load_lds width-16, unpadded lane-linear LDS).
// Epilogue: LDS-transpose to convert the 2-byte scatter stores (64/lane at
// 128 B stride — the r10 bottleneck) into 16 B/lane fully-coalesced streams.
// v^T tile is written to LDS transposed so its global writes are s-contiguous.
__global__ __launch_bounds__(256) void gemm_qkv(
    const bf16* __restrict__ hm,
    const bf16* __restrict__ WT0, const bf16* __restrict__ WT1, const bf16* __restrict__ WT2,
    const float* __restrict__ bq, const float* __restrict__ bk, const float* __restrict__ bv,
    bf16* __restrict__ outq, bf16* __restrict__ outk, bf16* __restrict__ outvT) {
  const int sel = blockIdx.z;
  const bf16* WT = sel == 0 ? WT0 : (sel == 1 ? WT1 : WT2);
  const float* bias = sel == 0 ? bq : (sel == 1 ? bk : bv);
  // 34816 B: first 16 KB double as As/Bs during the K-loop, whole thing as the
  // 128x136 bf16 C-tile (row stride 136 keeps 16 B alignment for b128 reads).
  __shared__ __align__(16) uint16_t SM[128 * 136];
  bf16* As = (bf16*)SM;            // 4096 bf16
  bf16* Bs = (bf16*)(SM + 4096);   // 4096 bf16
  int tid = threadIdx.x;
  int w = tid >> 6, lane = tid & 63, q4 = lane >> 4, l16 = lane & 15;
  int wr = w >> 1, wc = w & 1;
  int m0 = blockIdx.x * 128, n0 = blockIdx.y * 128;
  f32x4 acc[4][4];
#pragma unroll
  for (int i = 0; i < 4; i++)
#pragma unroll
    for (int j = 0; j < 4; j++) acc[i][j] = (f32x4){0.f, 0.f, 0.f, 0.f};

  for (int kc = 0; kc < 16; kc++) {
    int k0 = kc * 32;
#pragma unroll
    for (int u0 = 0; u0 < 2; u0++) {
      int e = u0 * 256 + tid;          // 16B unit; LDS dst = base + e*16B
      int row = e >> 2, c8 = (e & 3) * 8;
      stage16(&hm[(size_t)(m0 + row) * 512 + k0 + c8], &As[e * 8]);
      stage16(&WT[(size_t)(n0 + row) * 512 + k0 + c8], &Bs[e * 8]);
    }
    __syncthreads();
    bf16x8 af[4], bfr[4];
#pragma unroll
    for (int rt = 0; rt < 4; rt++)
      af[rt] = ld8(&As[(wr * 64 + rt * 16 + l16) * 32 + q4 * 8]);
#pragma unroll
    for (int nt = 0; nt < 4; nt++)
      bfr[nt] = ld8(&Bs[(wc * 64 + nt * 16 + l16) * 32 + q4 * 8]);
#pragma unroll
    for (int rt = 0; rt < 4; rt++)
#pragma unroll
      for (int nt = 0; nt < 4; nt++) acc[rt][nt] = MFMA16(af[rt], bfr[nt], acc[rt][nt]);
    __syncthreads();
  }

  if (sel != 2) {
    const float scale = sel == 0 ? 0.125f : 1.0f;
    // C-layout row-major into SM[row][col]
#pragma unroll
    for (int rt = 0; rt < 4; rt++)
#pragma unroll
      for (int nt = 0; nt < 4; nt++) {
        int ncol = wc * 64 + nt * 16 + l16;
        float bsv = bias[n0 + ncol];
#pragma unroll
        for (int r = 0; r < 4; r++) {
          int mrow = wr * 64 + rt * 16 + q4 * 4 + r;
          SM[mrow * 136 + ncol] = f2bu((acc[rt][nt][r] + bsv) * scale);
        }
      }
    __syncthreads();
    bf16* dst = sel == 0 ? outq : outk;
#pragma unroll
    for (int p = 0; p < 8; p++) {
      int e = p * 256 + tid;
      int row = e >> 4, c8 = (e & 15) * 8;
      bf16x8 vv = *(bf16x8*)&SM[row * 136 + c8];
      int gm = m0 + row, b_ = gm >> 9, s_ = gm & 511;
      int n = n0 + c8, hh = n >> 6, dh = n & 63;
      *(bf16x8*)(dst + ((size_t)((b_ * 8 + hh) * 512 + s_)) * 64 + dh) = vv;
    }
  } else {
    // transposed tile SM[ncol][mrow] so global writes are s-contiguous
#pragma unroll
    for (int rt = 0; rt < 4; rt++)
#pragma unroll
      for (int nt = 0; nt < 4; nt++) {
        int ncol = wc * 64 + nt * 16 + l16;
        float bsv = bias[n0 + ncol];
        union { uint16_t q[4]; uint2 u; } pk;
#pragma unroll
        for (int r = 0; r < 4; r++) pk.q[r] = f2bu(acc[rt][nt][r] + bsv);
        *(uint2*)&SM[ncol * 136 + wr * 64 + rt * 16 + q4 * 4] = pk.u;
      }
    __syncthreads();
#pragma unroll
    for (int p = 0; p < 8; p++) {
      int e = p * 256 + tid;
      int nn = e >> 4, s8 = (e & 15) * 8;
      bf16x8 vv = *(bf16x8*)&SM[nn * 136 + s8];
      int n = n0 + nn, hh = n >> 6, dh = n & 63;
      int gm = m0 + s8, b_ = gm >> 9, s_ = gm & 511;
      *(bf16x8*)(outvT + ((size_t)((b_ * 8 + hh) * 64 + dh)) * 512 + s_) = vv;
    }
  }
}

// ---------------------------------------------------------------- fused attention (r8 exact)
// Proven 52 us. Block = 4 waves x 64 q-rows x one bh; k/v staged cooperatively;
// scores in LDS ST; exp in place; 1/sum folded into epilogue; XCD swizzle.
__global__ __launch_bounds__(256, 2) void attn_fused(
    const bf16* __restrict__ q, const bf16* __restrict__ k, const bf16* __restrict__ vT,
    const uint32_t* __restrict__ tbits, const float* __restrict__ lg,
    const float* __restrict__ lb, bf16* __restrict__ ctx) {
  const int id = blockIdx.x;              // 0..1023
  const int xcd = id & 7;
  const int j = id >> 3;                  // 0..127
  const int mt = j & 7;                   // 8 m-tiles of 64 rows
  const int bh = ((j >> 3) << 3) | xcd;   // bh%8 == xcd
  const int m0 = mt * 64;
  const int b = bh >> 3, hh = bh & 7;
  const int tid = threadIdx.x;
  const int w = tid >> 6, lane = tid & 63, q4 = lane >> 4, l16 = lane & 15;

  __shared__ uint16_t ST[512][66];              // 67.6 KB: scores -> probs
  __shared__ __align__(16) bf16 SB[2][2560];    // 10 KB: k [32][72] / v [64][40]

  const bf16* qb = q + ((size_t)bh * 512 + m0 + w * 16) * 64;
  const bf16* kb = k + (size_t)bh * 512 * 64;
  const bf16* vb = vT + (size_t)bh * 64 * 512;

  bf16x8 aq0 = ld8(qb + (size_t)l16 * 64 + q4 * 8);
  bf16x8 aq1 = ld8(qb + (size_t)l16 * 64 + 32 + q4 * 8);

  uint32_t tb[4];
#pragma unroll
  for (int r = 0; r < 4; r++)
    tb[r] = tbits[((size_t)b * 512 + m0 + w * 16 + q4 * 4 + r) * 16 + l16];

  const int col = w * 16 + q4 * 4;

  {
    int key0 = tid >> 3, dh8 = (tid & 7) * 8;
    *(bf16x8*)&SB[0][key0 * 72 + dh8] = ld8(kb + (size_t)key0 * 64 + dh8);
  }
  __syncthreads();

  float s[4] = {0.f, 0.f, 0.f, 0.f}, s2[4] = {0.f, 0.f, 0.f, 0.f};
  for (int c = 0; c < 16; c++) {
    const int buf = c & 1;
    if (c < 15) {
      int key0 = tid >> 3, dh8 = (tid & 7) * 8;
      *(bf16x8*)&SB[buf ^ 1][key0 * 72 + dh8] =
          ld8(kb + (size_t)((c + 1) * 32 + key0) * 64 + dh8);
    }
#pragma unroll
    for (int kg = 0; kg < 2; kg++) {
      const bf16* kp = &SB[buf][(kg * 16 + l16) * 72];
      bf16x8 b0 = ld8(kp + q4 * 8);
      bf16x8 b1 = ld8(kp + 32 + q4 * 8);
      f32x4 acc = (f32x4){0.f, 0.f, 0.f, 0.f};
      acc = MFMA16(aq0, b0, acc);
      acc = MFMA16(aq1, b1, acc);
#pragma unroll
      for (int r = 0; r < 4; r++) {
        float v = acc[r];
        s[r] += v;
        s2[r] += v * v;
      }
      int key = c * 32 + kg * 16 + l16;
      *(uint32_t*)&ST[key][col] = (uint32_t)f2bu(acc[0]) | ((uint32_t)f2bu(acc[1]) << 16);
      *(uint32_t*)&ST[key][col + 2] = (uint32_t)f2bu(acc[2]) | ((uint32_t)f2bu(acc[3]) << 16);
    }
    __syncthreads();
  }

  float mean[4], rstd[4];
#pragma unroll
  for (int r = 0; r < 4; r++) {
    float a = s[r], a2 = s2[r];
#pragma unroll
    for (int mm = 1; mm < 16; mm <<= 1) {
      a += __shfl_xor(a, mm);
      a2 += __shfl_xor(a2, mm);
    }
    float mu = a * (1.0f / 512.0f);
    float var = a2 * (1.0f / 512.0f) - mu * mu;
    mean[r] = mu;
    rstd[r] = rsqrtf(var + 1e-5f);
  }

  float se[4] = {0.f, 0.f, 0.f, 0.f};
#pragma unroll
  for (int i = 0; i < 32; i++) {
    int key = i * 16 + l16;
    float g = lg[key], be = lb[key];
    uint32_t d0 = *(uint32_t*)&ST[key][col];
    uint32_t d1 = *(uint32_t*)&ST[key][col + 2];
    float v[4] = {bu2f(d0 & 0xffff), bu2f(d0 >> 16), bu2f(d1 & 0xffff), bu2f(d1 >> 16)};
    uint16_t p[4];
#pragma unroll
    for (int r = 0; r < 4; r++) {
      float t = (v[r] - mean[r]) * rstd[r] * g + be;
      t = ((tb[r] >> i) & 1u) ? t : -1.0e9f;
      float pf = __expf(t);
      se[r] += pf;
      p[r] = f2bu(pf);
    }
    *(uint32_t*)&ST[key][col] = (uint32_t)p[0] | ((uint32_t)p[1] << 16);
    *(uint32_t*)&ST[key][col + 2] = (uint32_t)p[2] | ((uint32_t)p[3] << 16);
  }
  float inv[4];
#pragma unroll
  for (int r = 0; r < 4; r++) {
    float a = se[r];
#pragma unroll
    for (int mm = 1; mm < 16; mm <<= 1) a += __shfl_xor(a, mm);
    inv[r] = 1.0f / a;
  }

  {
    int dh = tid >> 2, kk8 = (tid & 3) * 8;
    *(bf16x8*)&SB[0][dh * 40 + kk8] = ld8(vb + (size_t)dh * 512 + kk8);
  }
  __syncthreads();

  f32x4 o[4];
#pragma unroll
  for (int nt = 0; nt < 4; nt++) o[nt] = (f32x4){0.f, 0.f, 0.f, 0.f};

  for (int c = 0; c < 16; c++) {
    const int buf = c & 1;
    if (c < 15) {
      int dh = tid >> 2, kk8 = (tid & 3) * 8;
      *(bf16x8*)&SB[buf ^ 1][dh * 40 + kk8] =
          ld8(vb + (size_t)dh * 512 + (c + 1) * 32 + kk8);
    }
    union { uint16_t u[8]; bf16x8 v; } af;
#pragma unroll
    for (int jj = 0; jj < 8; jj++) af.u[jj] = ST[c * 32 + q4 * 8 + jj][w * 16 + l16];
#pragma unroll
    for (int nt = 0; nt < 4; nt++) {
      bf16x8 bv8 = ld8(&SB[buf][(nt * 16 + l16) * 40 + q4 * 8]);
      o[nt] = MFMA16(af.v, bv8, o[nt]);
    }
    __syncthreads();
  }

  bf16* cb = ctx + ((size_t)b * 512 + m0 + w * 16) * 512 + hh * 64;
#pragma unroll
  for (int nt = 0; nt < 4; nt++)
#pragma unroll
    for (int r = 0; r < 4; r++)
      cb[(size_t)(q4 * 4 + r) * 512 + nt * 16 + l16] = f2b(o[nt][r] * inv[r]);
}

// ---------------------------------------------------------------- out proj + residual (fp32 out)
__global__ __launch_bounds__(256) void gemm_out(
    const bf16* __restrict__ ctx, const bf16* __restrict__ WT,
    const float* __restrict__ bd, const float* __restrict__ x, float* __restrict__ out) {
  __shared__ __align__(16) bf16 As[128 * 32];
  __shared__ __align__(16) bf16 Bs[128 * 32];
  int tid = threadIdx.x;
  int w = tid >> 6, lane = tid & 63, q4 = lane >> 4, l16 = lane & 15;
  int wr = w >> 1, wc = w & 1;
  int m0 = blockIdx.x * 128, n0 = blockIdx.y * 128;
  f32x4 acc[4][4];
#pragma unroll
  for (int i = 0; i < 4; i++)
#pragma unroll
    for (int j = 0; j < 4; j++) acc[i][j] = (f32x4){0.f, 0.f, 0.f, 0.f};

  for (int kc = 0; kc < 16; kc++) {
    int k0 = kc * 32;
#pragma unroll
    for (int u0 = 0; u0 < 2; u0++) {
      int e = u0 * 256 + tid;
      int row = e >> 2, c8 = (e & 3) * 8;
      stage16(&ctx[(size_t)(m0 + row) * 512 + k0 + c8], &As[e * 8]);
      stage16(&WT[(size_t)(n0 + row) * 512 + k0 + c8], &Bs[e * 8]);
    }
    __syncthreads();
    bf16x8 af[4], bfr[4];
#pragma unroll
    for (int rt = 0; rt < 4; rt++)
      af[rt] = ld8(&As[(wr * 64 + rt * 16 + l16) * 32 + q4 * 8]);
#pragma unroll
    for (int nt = 0; nt < 4; nt++)
      bfr[nt] = ld8(&Bs[(wc * 64 + nt * 16 + l16) * 32 + q4 * 8]);
#pragma unroll
    for (int rt = 0; rt < 4; rt++)
#pragma unroll
      for (int nt = 0; nt < 4; nt++) acc[rt][nt] = MFMA16(af[rt], bfr[nt], acc[rt][nt]);
    __syncthreads();
  }
#pragma unroll
  for (int rt = 0; rt < 4; rt++) {
    int mbase = m0 + wr * 64 + rt * 16 + q4 * 4;
#pragma unroll
    for (int nt = 0; nt < 4; nt++) {
      int n = n0 + wc * 64 + nt * 16 + l16;
      float bsv = bd[n];
#pragma unroll
      for (int r = 0; r < 4; r++) {
        size_t idx = (size_t)(mbase + r) * 512 + n;
        out[idx] = acc[rt][nt][r] + bsv + x[idx];
      }
    }
  }
}

// ---------------------------------------------------------------- launch
extern "C" void kernel_launch(void* const* d_in, const int* in_sizes, int n_in,
                              void* d_out, int out_size, void* d_ws, size_t ws_size,
                              hipStream_t stream) {
  const float* x = (const float*)d_in[0];
  const int* mask = (const int*)d_in[1];
  const float* ln_g = (const float*)d_in[2];
  const float* ln_b = (const float*)d_in[3];
  const float* lna_g = (const float*)d_in[4];
  const float* lna_b = (const float*)d_in[5];
  const float* Wq = (const float*)d_in[6];
  const float* bq = (const float*)d_in[7];
  const float* Wk = (const float*)d_in[8];
  const float* bk = (const float*)d_in[9];
  const float* Wv = (const float*)d_in[10];
  const float* bv = (const float*)d_in[11];
  const float* Wd = (const float*)d_in[12];
  const float* bd = (const float*)d_in[13];

  char* ws = (char*)d_ws;
  const size_t MB = 1024 * 1024;
  if (ws_size < 44 * MB) return;
  bf16* h = (bf16*)(ws);                 // 8 MB  [8192,512]
  bf16* qd = (bf16*)(ws + 8 * MB);       // 8 MB  [B,H,S,DH]
  bf16* kd = (bf16*)(ws + 16 * MB);      // 8 MB  [B,H,S,DH]
  bf16* vTd = (bf16*)(ws + 24 * MB);     // 8 MB  [B,H,DH,S]
  bf16* ctx = (bf16*)(ws + 32 * MB);     // 8 MB  [B,S,D] bf16
  bf16* WqT = (bf16*)(ws + 40 * MB);
  bf16* WkT = (bf16*)(ws + 40 * MB + 512 * 1024);
  bf16* WvT = (bf16*)(ws + 40 * MB + 1024 * 1024);
  bf16* WdT = (bf16*)(ws + 40 * MB + 1536 * 1024);
  uint32_t* tbits = (uint32_t*)(ws + 42 * MB);  // 512 KB

  transpose512<<<dim3(16, 16, 4), dim3(32, 8), 0, stream>>>(Wq, Wk, Wv, Wd, WqT, WkT, WvT, WdT);
  mask_bits<<<512, 256, 0, stream>>>(mask, tbits);
  ln_rows<<<8192, 256, 0, stream>>>(x, ln_g, ln_b, h);
  gemm_qkv<<<dim3(64, 4, 3), 256, 0, stream>>>(h, WqT, WkT, WvT, bq, bk, bv, qd, kd, vTd);
  attn_fused<<<1024, 256, 0, stream>>>(qd, kd, vTd, tbits, lna_g, lna_b, ctx);
  gemm_out<<<dim3(64, 4), 256, 0, stream>>>(ctx, WdT, bd, x, (float*)d_out);
}

// Round 12
// 186.160 us; speedup vs baseline: 1.2538x; 1.0193x over previous
//
#include <hip/hip_runtime.h>
#include <hip/hip_bf16.h>
#include <stdint.h>

// B=16, S=512, D=512, H=8, DH=64. Float tensors fp32; mask int32; out fp32.
// Internals: bf16 MFMA operands, fp32 accumulation.

typedef __hip_bfloat16 bf16;
typedef __bf16 bf16x8 __attribute__((ext_vector_type(8)));
typedef float f32x4 __attribute__((ext_vector_type(4)));

#define MFMA16(a, b, c) __builtin_amdgcn_mfma_f32_16x16x32_bf16((a), (b), (c), 0, 0, 0)
// Compiler-only fence (r7-proven): stops LLVM hoisting same-wave cross-lane
// ds_reads above ds_writes; zero instructions, global loads stay in flight.
#define WAVE_LDS_FENCE() asm volatile("" ::: "memory")

static __device__ __forceinline__ bf16 f2b(float v) { return __float2bfloat16(v); }
static __device__ __forceinline__ bf16x8 ld8(const bf16* p) { return *(const bf16x8*)p; }
static __device__ __forceinline__ uint16_t f2bu(float v) {
  return __hip_bfloat16_raw(__float2bfloat16(v)).x;
}
static __device__ __forceinline__ float bu2f(uint32_t u) {
  union { uint32_t i; float f; } c;
  c.i = u << 16;
  return c.f;
}
// m97-style async global->LDS, 16 B/lane (wave-uniform base + lane*16).
static __device__ __forceinline__ void stage16(const bf16* g, bf16* l) {
  __builtin_amdgcn_global_load_lds(
      (const __attribute__((address_space(1))) void*)g,
      (__attribute__((address_space(3))) void*)l, 16, 0, 0);
}

// ---------------------------------------------------------------- transpose + cast
__global__ __launch_bounds__(256) void transpose512(
    const float* __restrict__ W0, const float* __restrict__ W1,
    const float* __restrict__ W2, const float* __restrict__ W3,
    bf16* __restrict__ T0, bf16* __restrict__ T1,
    bf16* __restrict__ T2, bf16* __restrict__ T3) {
  __shared__ float t[32][33];
  const float* src; bf16* dst;
  switch (blockIdx.z) {
    case 0: src = W0; dst = T0; break;
    case 1: src = W1; dst = T1; break;
    case 2: src = W2; dst = T2; break;
    default: src = W3; dst = T3; break;
  }
  int tx = threadIdx.x, ty = threadIdx.y;  // 32 x 8
  int n0 = blockIdx.x * 32, k0 = blockIdx.y * 32;
#pragma unroll
  for (int i = 0; i < 4; i++) {
    int kk = ty * 4 + i;
    t[kk][tx] = src[(k0 + kk) * 512 + n0 + tx];
  }
  __syncthreads();
#pragma unroll
  for (int i = 0; i < 4; i++) {
    int nn = ty * 4 + i;
    dst[(n0 + nn) * 512 + k0 + tx] = f2b(t[tx][nn]);
  }
}

// ---------------------------------------------------------------- mask -> bitmask
// Coalesced ballot pack (r2-proven; r10's fused strided version over-fetched
// 4x from HBM). bits[e/32] bit (e%32) = (mask[e] != 0), e row-major [B,S,S].
__global__ __launch_bounds__(256) void mask_pack(const int* __restrict__ mask,
                                                 uint32_t* __restrict__ bits) {
  size_t t = (size_t)blockIdx.x * 256 + threadIdx.x;
  int mv = mask[t];
  unsigned long long bal = __ballot(mv != 0);
  if ((threadIdx.x & 63) == 0) {
    ((unsigned long long*)bits)[t >> 6] = bal;
  }
}

// ---------------------------------------------------------------- LayerNorm(x) -> h (bf16)
__global__ __launch_bounds__(256) void ln_rows(
    const float* __restrict__ x, const float* __restrict__ g,
    const float* __restrict__ be, bf16* __restrict__ h) {
  int row = blockIdx.x;
  int tid = threadIdx.x;
  const float* xr = x + (size_t)row * 512;
  float v0 = xr[tid], v1 = xr[tid + 256];
  float s = v0 + v1, s2 = v0 * v0 + v1 * v1;
#pragma unroll
  for (int m = 1; m < 64; m <<= 1) {
    s += __shfl_xor(s, m);
    s2 += __shfl_xor(s2, m);
  }
  __shared__ float rs[4], rs2[4];
  int w = tid >> 6;
  if ((tid & 63) == 0) { rs[w] = s; rs2[w] = s2; }
  __syncthreads();
  s = rs[0] + rs[1] + rs[2] + rs[3];
  s2 = rs2[0] + rs2[1] + rs2[2] + rs2[3];
  float mean = s * (1.0f / 512.0f);
  float var = s2 * (1.0f / 512.0f) - mean * mean;
  float rstd = rsqrtf(var + 1e-5f);
  bf16* hr = h + (size_t)row * 512;
  hr[tid] = f2b((v0 - mean) * rstd * g[tid] + be[tid]);
  hr[tid + 256] = f2b((v1 - mean) * rstd * g[tid + 256] + be[tid + 256]);
}

// ---------------------------------------------------------------- QKV GEMM (r11-proven)
__global__ __launch_bounds__(256) void gemm_qkv(
    const bf16* __restrict__ hm,
    const bf16* __restrict__ WT0, const bf16* __restrict__ WT1, const bf16* __restrict__ WT2,
    const float* __restrict__ bq, const float* __restrict__ bk, const float* __restrict__ bv,
    bf16* __restrict__ outq, bf16* __restrict__ outk, bf16* __restrict__ outvT) {
  const int sel = blockIdx.z;
  const bf16* WT = sel == 0 ? WT0 : (sel == 1 ? WT1 : WT2);
  const float* bias = sel == 0 ? bq : (sel == 1 ? bk : bv);
  __shared__ __align__(16) uint16_t SM[128 * 136];
  bf16* As = (bf16*)SM;
  bf16* Bs = (bf16*)(SM + 4096);
  int tid = threadIdx.x;
  int w = tid >> 6, lane = tid & 63, q4 = lane >> 4, l16 = lane & 15;
  int wr = w >> 1, wc = w & 1;
  int m0 = blockIdx.x * 128, n0 = blockIdx.y * 128;
  f32x4 acc[4][4];
#pragma unroll
  for (int i = 0; i < 4; i++)
#pragma unroll
    for (int j = 0; j < 4; j++) acc[i][j] = (f32x4){0.f, 0.f, 0.f, 0.f};

  for (int kc = 0; kc < 16; kc++) {
    int k0 = kc * 32;
#pragma unroll
    for (int u0 = 0; u0 < 2; u0++) {
      int e = u0 * 256 + tid;
      int row = e >> 2, c8 = (e & 3) * 8;
      stage16(&hm[(size_t)(m0 + row) * 512 + k0 + c8], &As[e * 8]);
      stage16(&WT[(size_t)(n0 + row) * 512 + k0 + c8], &Bs[e * 8]);
    }
    __syncthreads();
    bf16x8 af[4], bfr[4];
#pragma unroll
    for (int rt = 0; rt < 4; rt++)
      af[rt] = ld8(&As[(wr * 64 + rt * 16 + l16) * 32 + q4 * 8]);
#pragma unroll
    for (int nt = 0; nt < 4; nt++)
      bfr[nt] = ld8(&Bs[(wc * 64 + nt * 16 + l16) * 32 + q4 * 8]);
#pragma unroll
    for (int rt = 0; rt < 4; rt++)
#pragma unroll
      for (int nt = 0; nt < 4; nt++) acc[rt][nt] = MFMA16(af[rt], bfr[nt], acc[rt][nt]);
    __syncthreads();
  }

  if (sel != 2) {
    const float scale = sel == 0 ? 0.125f : 1.0f;
#pragma unroll
    for (int rt = 0; rt < 4; rt++)
#pragma unroll
      for (int nt = 0; nt < 4; nt++) {
        int ncol = wc * 64 + nt * 16 + l16;
        float bsv = bias[n0 + ncol];
#pragma unroll
        for (int r = 0; r < 4; r++) {
          int mrow = wr * 64 + rt * 16 + q4 * 4 + r;
          SM[mrow * 136 + ncol] = f2bu((acc[rt][nt][r] + bsv) * scale);
        }
      }
    __syncthreads();
    bf16* dst = sel == 0 ? outq : outk;
#pragma unroll
    for (int p = 0; p < 8; p++) {
      int e = p * 256 + tid;
      int row = e >> 4, c8 = (e & 15) * 8;
      bf16x8 vv = *(bf16x8*)&SM[row * 136 + c8];
      int gm = m0 + row, b_ = gm >> 9, s_ = gm & 511;
      int n = n0 + c8, hh = n >> 6, dh = n & 63;
      *(bf16x8*)(dst + ((size_t)((b_ * 8 + hh) * 512 + s_)) * 64 + dh) = vv;
    }
  } else {
#pragma unroll
    for (int rt = 0; rt < 4; rt++)
#pragma unroll
      for (int nt = 0; nt < 4; nt++) {
        int ncol = wc * 64 + nt * 16 + l16;
        float bsv = bias[n0 + ncol];
        union { uint16_t q[4]; uint2 u; } pk;
#pragma unroll
        for (int r = 0; r < 4; r++) pk.q[r] = f2bu(acc[rt][nt][r] + bsv);
        *(uint2*)&SM[ncol * 136 + wr * 64 + rt * 16 + q4 * 4] = pk.u;
      }
    __syncthreads();
#pragma unroll
    for (int p = 0; p < 8; p++) {
      int e = p * 256 + tid;
      int nn = e >> 4, s8 = (e & 15) * 8;
      bf16x8 vv = *(bf16x8*)&SM[nn * 136 + s8];
      int n = n0 + nn, hh = n >> 6, dh = n & 63;
      int gm = m0 + s8, b_ = gm >> 9, s_ = gm & 511;
      *(bf16x8*)(outvT + ((size_t)((b_ * 8 + hh) * 64 + dh)) * 512 + s_) = vv;
    }
  }
}

// ---------------------------------------------------------------- fused attention v10
// r8 structure, but phase 2 (LN+mask+exp LDS pass over ST) is folded into
// phase 3's per-element read path: stats cross the lane permutation via SMR
// (same-wave LDS + fence), gamma/beta via GB (broadcast reads), mask bits in
// rbits[16] registers (row-major bits: key c*32+q4*8+jj -> dword c, bit
// q4*8+jj). Removes one full LDS pass over the score matrix and lengthens
// the phase-3 chunk body (hides staging-load latency). LDS 80384 B -> 2/CU.
__global__ __launch_bounds__(256, 2) void attn_fused(
    const bf16* __restrict__ q, const bf16* __restrict__ k, const bf16* __restrict__ vT,
    const uint32_t* __restrict__ bits, const float* __restrict__ lg,
    const float* __restrict__ lb, bf16* __restrict__ ctx) {
  const int id = blockIdx.x;              // 0..1023
  const int xcd = id & 7;
  const int j = id >> 3;                  // 0..127
  const int mt = j & 7;                   // 8 m-tiles of 64 rows
  const int bh = ((j >> 3) << 3) | xcd;   // bh%8 == xcd
  const int m0 = mt * 64;
  const int b = bh >> 3, hh = bh & 7;
  const int tid = threadIdx.x;
  const int w = tid >> 6, lane = tid & 63, q4 = lane >> 4, l16 = lane & 15;

  __shared__ uint16_t ST[512][66];              // 67584 B raw scores (bf16 bits)
  __shared__ __align__(16) bf16 SB[2][2560];    // 10240 B k/v staging
  __shared__ uint32_t GB[512];                  // 2048 B {g,b} bf16-packed
  __shared__ float SMR[4][16][2];               // 512 B per-wave {mean,rstd}

  GB[tid] = (uint32_t)f2bu(lg[tid]) | ((uint32_t)f2bu(lb[tid]) << 16);
  GB[tid + 256] = (uint32_t)f2bu(lg[tid + 256]) | ((uint32_t)f2bu(lb[tid + 256]) << 16);

  const bf16* qb = q + ((size_t)bh * 512 + m0 + w * 16) * 64;
  const bf16* kb = k + (size_t)bh * 512 * 64;
  const bf16* vb = vT + (size_t)bh * 64 * 512;

  bf16x8 aq0 = ld8(qb + (size_t)l16 * 64 + q4 * 8);
  bf16x8 aq1 = ld8(qb + (size_t)l16 * 64 + 32 + q4 * 8);

  // this lane's phase-3 q-row and its 512 mask bits (16 dwords, registers)
  const int myrow = m0 + w * 16 + l16;
  uint32_t rbits[16];
#pragma unroll
  for (int c = 0; c < 16; c++)
    rbits[c] = bits[((size_t)b * 512 + myrow) * 16 + c];

  {
    int key0 = tid >> 3, dh8 = (tid & 7) * 8;
    *(bf16x8*)&SB[0][key0 * 72 + dh8] = ld8(kb + (size_t)key0 * 64 + dh8);
  }
  __syncthreads();  // covers GB writes + k chunk 0

  // ---- phase 1: QK^T -> ST (raw bf16 scores), stats in registers
  float s[4] = {0.f, 0.f, 0.f, 0.f}, s2[4] = {0.f, 0.f, 0.f, 0.f};
  const int col = w * 16 + q4 * 4;
  for (int c = 0; c < 16; c++) {
    const int buf = c & 1;
    if (c < 15) {
      int key0 = tid >> 3, dh8 = (tid & 7) * 8;
      *(bf16x8*)&SB[buf ^ 1][key0 * 72 + dh8] =
          ld8(kb + (size_t)((c + 1) * 32 + key0) * 64 + dh8);
    }
#pragma unroll
    for (int kg = 0; kg < 2; kg++) {
      const bf16* kp = &SB[buf][(kg * 16 + l16) * 72];
      bf16x8 b0 = ld8(kp + q4 * 8);
      bf16x8 b1 = ld8(kp + 32 + q4 * 8);
      f32x4 acc = (f32x4){0.f, 0.f, 0.f, 0.f};
      acc = MFMA16(aq0, b0, acc);
      acc = MFMA16(aq1, b1, acc);
#pragma unroll
      for (int r = 0; r < 4; r++) {
        float v = acc[r];
        s[r] += v;
        s2[r] += v * v;
      }
      int key = c * 32 + kg * 16 + l16;
      *(uint32_t*)&ST[key][col] = (uint32_t)f2bu(acc[0]) | ((uint32_t)f2bu(acc[1]) << 16);
      *(uint32_t*)&ST[key][col + 2] = (uint32_t)f2bu(acc[2]) | ((uint32_t)f2bu(acc[3]) << 16);
    }
    __syncthreads();
  }

  // ---- stats, published per-row via SMR (same-wave cross-lane, fence only)
  float mean[4], rstd[4];
#pragma unroll
  for (int r = 0; r < 4; r++) {
    float a = s[r], a2 = s2[r];
#pragma unroll
    for (int mm = 1; mm < 16; mm <<= 1) {
      a += __shfl_xor(a, mm);
      a2 += __shfl_xor(a2, mm);
    }
    float mu = a * (1.0f / 512.0f);
    float var = a2 * (1.0f / 512.0f) - mu * mu;
    mean[r] = mu;
    rstd[r] = rsqrtf(var + 1e-5f);
  }
  if (l16 == 0) {
#pragma unroll
    for (int r = 0; r < 4; r++) {
      SMR[w][q4 * 4 + r][0] = mean[r];
      SMR[w][q4 * 4 + r][1] = rstd[r];
    }
  }
  WAVE_LDS_FENCE();
  const float mrow = SMR[w][l16][0];
  const float rrow = SMR[w][l16][1];

  // ---- phase 3: LN+mask+exp at read, PV MFMA; v staged chunk-wise
  {
    int dh = tid >> 2, kk8 = (tid & 3) * 8;
    *(bf16x8*)&SB[0][dh * 40 + kk8] = ld8(vb + (size_t)dh * 512 + kk8);
  }
  __syncthreads();

  f32x4 o[4];
#pragma unroll
  for (int nt = 0; nt < 4; nt++) o[nt] = (f32x4){0.f, 0.f, 0.f, 0.f};
  float se = 0.f;

#pragma unroll
  for (int c = 0; c < 16; c++) {
    const int buf = c & 1;
    if (c < 15) {
      int dh = tid >> 2, kk8 = (tid & 3) * 8;
      *(bf16x8*)&SB[buf ^ 1][dh * 40 + kk8] =
          ld8(vb + (size_t)dh * 512 + (c + 1) * 32 + kk8);
    }
    const uint32_t mb = rbits[c];
    union { uint16_t u[8]; bf16x8 v; } af;
#pragma unroll
    for (int jj = 0; jj < 8; jj++) {
      int key = c * 32 + q4 * 8 + jj;
      float sv = bu2f(ST[key][w * 16 + l16]);
      uint32_t gb = GB[key];
      float t = (sv - mrow) * rrow * bu2f(gb & 0xffffu) + bu2f(gb >> 16);
      t = ((mb >> (q4 * 8 + jj)) & 1u) ? t : -1.0e9f;
      float p = __expf(t);
      se += p;
      af.u[jj] = f2bu(p);
    }
#pragma unroll
    for (int nt = 0; nt < 4; nt++) {
      bf16x8 bv8 = ld8(&SB[buf][(nt * 16 + l16) * 40 + q4 * 8]);
      o[nt] = MFMA16(af.v, bv8, o[nt]);
    }
    __syncthreads();
  }

  // row-sum: lane covers keys == (q4*8..q4*8+7 mod 32) of row w*16+l16;
  // combine the 4 q4 copies, then remap inv to C-layout rows q4*4+r.
  se += __shfl_xor(se, 16);
  se += __shfl_xor(se, 32);
  float invr = 1.0f / se;
  float inv[4];
#pragma unroll
  for (int r = 0; r < 4; r++) inv[r] = __shfl(invr, q4 * 4 + r);

  bf16* cb = ctx + ((size_t)b * 512 + m0 + w * 16) * 512 + hh * 64;
#pragma unroll
  for (int nt = 0; nt < 4; nt++)
#pragma unroll
    for (int r = 0; r < 4; r++)
      cb[(size_t)(q4 * 4 + r) * 512 + nt * 16 + l16] = f2b(o[nt][r] * inv[r]);
}

// ---------------------------------------------------------------- out proj + residual (fp32 out)
__global__ __launch_bounds__(256) void gemm_out(
    const bf16* __restrict__ ctx, const bf16* __restrict__ WT,
    const float* __restrict__ bd, const float* __restrict__ x, float* __restrict__ out) {
  __shared__ __align__(16) bf16 As[128 * 32];
  __shared__ __align__(16) bf16 Bs[128 * 32];
  int tid = threadIdx.x;
  int w = tid >> 6, lane = tid & 63, q4 = lane >> 4, l16 = lane & 15;
  int wr = w >> 1, wc = w & 1;
  int m0 = blockIdx.x * 128, n0 = blockIdx.y * 128;
  f32x4 acc[4][4];
#pragma unroll
  for (int i = 0; i < 4; i++)
#pragma unroll
    for (int j = 0; j < 4; j++) acc[i][j] = (f32x4){0.f, 0.f, 0.f, 0.f};

  for (int kc = 0; kc < 16; kc++) {
    int k0 = kc * 32;
#pragma unroll
    for (int u0 = 0; u0 < 2; u0++) {
      int e = u0 * 256 + tid;
      int row = e >> 2, c8 = (e & 3) * 8;
      stage16(&ctx[(size_t)(m0 + row) * 512 + k0 + c8], &As[e * 8]);
      stage16(&WT[(size_t)(n0 + row) * 512 + k0 + c8], &Bs[e * 8]);
    }
    __syncthreads();
    bf16x8 af[4], bfr[4];
#pragma unroll
    for (int rt = 0; rt < 4; rt++)
      af[rt] = ld8(&As[(wr * 64 + rt * 16 + l16) * 32 + q4 * 8]);
#pragma unroll
    for (int nt = 0; nt < 4; nt++)
      bfr[nt] = ld8(&Bs[(wc * 64 + nt * 16 + l16) * 32 + q4 * 8]);
#pragma unroll
    for (int rt = 0; rt < 4; rt++)
#pragma unroll
      for (int nt = 0; nt < 4; nt++) acc[rt][nt] = MFMA16(af[rt], bfr[nt], acc[rt][nt]);
    __syncthreads();
  }
#pragma unroll
  for (int rt = 0; rt < 4; rt++) {
    int mbase = m0 + wr * 64 + rt * 16 + q4 * 4;
#pragma unroll
    for (int nt = 0; nt < 4; nt++) {
      int n = n0 + wc * 64 + nt * 16 + l16;
      float bsv = bd[n];
#pragma unroll
      for (int r = 0; r < 4; r++) {
        size_t idx = (size_t)(mbase + r) * 512 + n;
        out[idx] = acc[rt][nt][r] + bsv + x[idx];
      }
    }
  }
}

// ---------------------------------------------------------------- launch
extern "C" void kernel_launch(void* const* d_in, const int* in_sizes, int n_in,
                              void* d_out, int out_size, void* d_ws, size_t ws_size,
                              hipStream_t stream) {
  const float* x = (const float*)d_in[0];
  const int* mask = (const int*)d_in[1];
  const float* ln_g = (const float*)d_in[2];
  const float* ln_b = (const float*)d_in[3];
  const float* lna_g = (const float*)d_in[4];
  const float* lna_b = (const float*)d_in[5];
  const float* Wq = (const float*)d_in[6];
  const float* bq = (const float*)d_in[7];
  const float* Wk = (const float*)d_in[8];
  const float* bk = (const float*)d_in[9];
  const float* Wv = (const float*)d_in[10];
  const float* bv = (const float*)d_in[11];
  const float* Wd = (const float*)d_in[12];
  const float* bd = (const float*)d_in[13];

  char* ws = (char*)d_ws;
  const size_t MB = 1024 * 1024;
  if (ws_size < 44 * MB) return;
  bf16* h = (bf16*)(ws);                 // 8 MB  [8192,512]
  bf16* qd = (bf16*)(ws + 8 * MB);       // 8 MB  [B,H,S,DH]
  bf16* kd = (bf16*)(ws + 16 * MB);      // 8 MB  [B,H,S,DH]
  bf16* vTd = (bf16*)(ws + 24 * MB);     // 8 MB  [B,H,DH,S]
  bf16* ctx = (bf16*)(ws + 32 * MB);     // 8 MB  [B,S,D] bf16
  bf16* WqT = (bf16*)(ws + 40 * MB);
  bf16* WkT = (bf16*)(ws + 40 * MB + 512 * 1024);
  bf16* WvT = (bf16*)(ws + 40 * MB + 1024 * 1024);
  bf16* WdT = (bf16*)(ws + 40 * MB + 1536 * 1024);
  uint32_t* bits = (uint32_t*)(ws + 42 * MB);  // 512 KB

  transpose512<<<dim3(16, 16, 4), dim3(32, 8), 0, stream>>>(Wq, Wk, Wv, Wd, WqT, WkT, WvT, WdT);
  mask_pack<<<16384, 256, 0, stream>>>(mask, bits);
  ln_rows<<<8192, 256, 0, stream>>>(x, ln_g, ln_b, h);
  gemm_qkv<<<dim3(64, 4, 3), 256, 0, stream>>>(h, WqT, WkT, WvT, bq, bk, bv, qd, kd, vTd);
  attn_fused<<<1024, 256, 0, stream>>>(qd, kd, vTd, bits, lna_g, lna_b, ctx);
  gemm_out<<<dim3(64, 4), 256, 0, stream>>>(ctx, WdT, bd, x, (float*)d_out);
}